// Round 10
// baseline (126764.893 us; speedup 1.0000x reference)
//
#include <hip/hip_runtime.h>
#include <cstddef>

#define T_LEN 32768
#define HID   300
#define HP    304   // padded row width for x/h buffers
#define HK    320   // padded K for MFMA (10 chunks of 32)
#define KC    10
#define IN_D  500
#define OUT_D 100
#define OUTP  104
#define DIST  4     // x prefetch distance (steps) = slot count
#define CHUNK 64
#define NCHUNK (T_LEN / CHUNK)
#define NWAVE 12    // 768 threads, 3 waves/SIMD

typedef _Float16 f16x8 __attribute__((ext_vector_type(8)));
typedef float    f32x4 __attribute__((ext_vector_type(4)));

// Static device scratch
__device__ __align__(16) float    g_x  [(size_t)(T_LEN + 8) * HP];    // x0
__device__ __align__(16) float    g_x1 [(size_t)(T_LEN + 8) * HP];    // x1
__device__ __align__(16) _Float16 g_h0h[(size_t)T_LEN * HP + 64];     // h0, f16
__device__ __align__(16) _Float16 g_h1h[(size_t)T_LEN * HP + 64];     // h1, f16
__device__ __align__(16) float    g_wt0[IN_D * HP];
__device__ __align__(16) float    g_wtl[HID * OUTP];
__device__ int g_flag0;   // chunks of h0 published by scan0
__device__ int g_flag1;   // chunks of x1 published by proj1

// ---------------- reset flags (graph replays!) ----------------
__global__ void k_reset() { g_flag0 = 0; g_flag1 = 0; }

// ---------------- transpose + pad: dst[k][j] = (j<J) ? src[j][k] : 0 ----------------
__global__ void k_transpose(const float* __restrict__ src, int J, int K, int JP, int dst_sel)
{
    float* dst = (dst_sel == 0) ? g_wt0 : g_wtl;
    int idx = blockIdx.x * 256 + threadIdx.x;
    if (idx >= K * JP) return;
    int k = idx / JP, j = idx - k * JP;
    dst[idx] = (j < J) ? src[j * K + k] : 0.f;
}

// ---------------- x0 = input @ W_ih0^T + (b_ih0+b_hh0), 32 rows per block ----------------
__global__ __launch_bounds__(320) void k_gemm_in(const float* __restrict__ inp,
                                                 const float* __restrict__ b1,
                                                 const float* __restrict__ b2)
{
    __shared__ float lds[32 * IN_D];
    const int tid = threadIdx.x;
    const int t0  = blockIdx.x * 32;
    {
        const f32x4* src4 = (const f32x4*)(inp + (size_t)t0 * IN_D);
        f32x4* lds4 = (f32x4*)lds;
        const int n4 = (32 * IN_D) >> 2;
        for (int i = tid; i < n4; i += 320) lds4[i] = src4[i];
    }
    __syncthreads();
    const int j = tid;
    if (j >= HP) return;
    float acc[32];
#pragma unroll
    for (int i = 0; i < 32; i++) acc[i] = 0.f;
#pragma unroll 4
    for (int k = 0; k < IN_D; k++) {
        float w = g_wt0[k * HP + j];
#pragma unroll
        for (int i = 0; i < 32; i++) acc[i] += w * lds[i * IN_D + k];  // uniform addr -> broadcast
    }
    const float bias = (j < HID) ? (b1[j] + b2[j]) : 0.f;
#pragma unroll 4
    for (int i = 0; i < 32; i++) g_x[(size_t)(t0 + i) * HP + j] = acc[i] + bias;
}

// ---------------- out = h1(f16) @ WTl + b_lin, 64 rows per block ----------------
__global__ __launch_bounds__(128) void k_gemm_out(const float* __restrict__ blin,
                                                  float* __restrict__ out)
{
    __shared__ float lds[64 * HP];
    const int tid = threadIdx.x;
    const int t0  = blockIdx.x * 64;
    {
        const f16x8* src8 = (const f16x8*)(g_h1h + (size_t)t0 * HP);
        const int n8 = (64 * HP) / 8;
        for (int i = tid; i < n8; i += 128) {
            f16x8 v = src8[i];
            float* d = &lds[i * 8];
#pragma unroll
            for (int e = 0; e < 8; e++) d[e] = (float)v[e];
        }
    }
    __syncthreads();
    const int j = tid;
    if (j >= OUTP) return;
    float acc[64];
#pragma unroll
    for (int i = 0; i < 64; i++) acc[i] = 0.f;
#pragma unroll 2
    for (int k = 0; k < HID; k++) {
        float w = g_wtl[k * OUTP + j];
#pragma unroll
        for (int i = 0; i < 64; i++) acc[i] += w * lds[i * HP + k];
    }
    if (j < OUT_D) {
        float b = blin[j];
        for (int i = 0; i < 64; i++) out[(size_t)(t0 + i) * OUT_D + j] = acc[i] + b;
    }
}

// ---------------- helpers ----------------
__device__ __forceinline__ float fast_tanh(float v)
{
    float e = __expf(2.f * v);
    return 1.f - 2.f * __builtin_amdgcn_rcpf(e + 1.f);
}

// W row-tile fragment as f16: lane holds row = tile*16+col, k = kc*32+g*8+j; OOB zeroed.
// Same register contents serve as A-frag (row=l&15) or B-frag (col=l&15).
__device__ __forceinline__ f16x8 loadw_frag(const float* __restrict__ W,
                                            int tile, int col, int g, int kc)
{
    const int row = tile * 16 + col;
    const int kb  = kc * 32 + g * 8;
    f16x8 f;
#pragma unroll
    for (int j = 0; j < 8; j++) {
        const int k = kb + j;
        float wv = (row < HID && k < HID) ? W[row * HID + k] : 0.f;
        f[j] = (_Float16)wv;
    }
    return f;
}

// consumer: tid0 spins with agent-scope acquire (buffer_inv), then block-wide barrier
__device__ __forceinline__ void wait_flag(int* f, int target)
{
    if (threadIdx.x == 0) {
        while (__hip_atomic_load(f, __ATOMIC_ACQUIRE, __HIP_MEMORY_SCOPE_AGENT) < target)
            __builtin_amdgcn_s_sleep(8);
    }
    __syncthreads();
}

// producer: __syncthreads drains each wave's vmcnt; release store (wbl2) publishes
__device__ __forceinline__ void publish_flag(int* f, int v)
{
    __syncthreads();
    if (threadIdx.x == 0)
        __hip_atomic_store(f, v, __ATOMIC_RELEASE, __HIP_MEMORY_SCOPE_AGENT);
}

#define MF(a_, b_, c_) __builtin_amdgcn_mfma_f32_16x16x32_f16((a_), (b_), (c_), 0, 0, 0)

// ---------------- scan role: h_t = tanh(x_t + Whh h_{t-1}) ----------------
// 12 waves (3/SIMD). 19 row-tiles of 16: wave w owns tile w; waves 0-6 also tile 12+w.
// OPERAND-SWAPPED MFMA: D = h(A) x W^T(B) -> D[row][col] = y[tile*16+col] for every
// row. Lane's 4 C-regs are identical copies -> extract = acc[0]; cross-chain sum is
// scalar; writers are lanes 0-15. 5 chains of depth 2 (kc pairs) cut dependent-MFMA
// latency 5L -> 2L. Scalar x slots (DIST=4), one lgkmcnt+s_barrier per step, vmcnt
// never drained in-loop.
template<int ROLE0>
__device__ __forceinline__ void scan_role(_Float16 (*hlds)[HK],
                                          const float* __restrict__ Whh,
                                          const float* __restrict__ xin,
                                          _Float16* __restrict__ hseq)
{
    const int tid  = threadIdx.x;
    const int lane = tid & 63;
    const int wave = tid >> 6;       // 0..11
    const int col  = lane & 15;
    const int g    = lane >> 4;      // 0..3
    const bool writer = (lane < 16); // group 0 holds replica row-group 0

    const int tA = wave, tB = wave + NWAVE;
    const bool hasB = (wave < 7);            // tiles 12..18
    const int cA = tA * 16 + col;            // output row this lane finalizes (<=191)
    const int cB = tB * 16 + col;            // <=303 (< HP, no guard needed)

    for (int i = tid; i < 2 * HK; i += 64 * NWAVE) ((_Float16*)hlds)[i] = (_Float16)0.f;

    f16x8 wA[KC], wB[KC];
#pragma unroll
    for (int kc = 0; kc < KC; kc++) {
        wA[kc] = loadw_frag(Whh, tA, col, g, kc);
        if (hasB) wB[kc] = loadw_frag(Whh, tB, col, g, kc);
        else {
            f16x8 z;
#pragma unroll
            for (int j = 0; j < 8; j++) z[j] = (_Float16)0.f;
            wB[kc] = z;
        }
    }

    __syncthreads();

    if (!ROLE0) wait_flag(&g_flag1, NCHUNK < 2 ? NCHUNK : 2);  // chunks 0,1 of x1 ready

    // x prefetch slots: slot s holds x for the next step t with (t & 3) == s
    float xA[DIST], xB[DIST];
#pragma unroll
    for (int s = 0; s < DIST; s++) {
        xA[s] = xin[(size_t)s * HP + cA];
        xB[s] = hasB ? xin[(size_t)s * HP + cB] : 0.f;
    }

    const f32x4 Z = {0.f, 0.f, 0.f, 0.f};

// One timestep. bf reads first; slot consumed, refilled for t+DIST; 5 chains of
// depth 2 per tile (operand-swapped), scalar tree-sum of acc[0]s; tanh; writer
// lanes (0-15) publish f16 h to hlds[1-R] and global.
#define STEP(t_, R_, s_) do {                                                          \
        f16x8 bf[KC];                                                                  \
        _Pragma("unroll")                                                              \
        for (int kc = 0; kc < KC; kc++)                                                \
            bf[kc] = *(const f16x8*)&hlds[R_][kc * 32 + g * 8];                        \
        float xvA = xA[s_], xvB = xB[s_];                                              \
        xA[s_] = xin[(size_t)((t_) + DIST) * HP + cA];                                 \
        if (hasB) xB[s_] = xin[(size_t)((t_) + DIST) * HP + cB];                       \
        f32x4 cAa[5], cBb[5];                                                          \
        _Pragma("unroll")                                                              \
        for (int c5 = 0; c5 < 5; c5++) {                                               \
            cAa[c5] = MF(bf[2 * c5], wA[2 * c5], Z);                                   \
            if (hasB) cBb[c5] = MF(bf[2 * c5], wB[2 * c5], Z);                         \
        }                                                                              \
        _Pragma("unroll")                                                              \
        for (int c5 = 0; c5 < 5; c5++) {                                               \
            cAa[c5] = MF(bf[2 * c5 + 1], wA[2 * c5 + 1], cAa[c5]);                     \
            if (hasB) cBb[c5] = MF(bf[2 * c5 + 1], wB[2 * c5 + 1], cBb[c5]);           \
        }                                                                              \
        float sA = ((cAa[0][0] + cAa[1][0]) + (cAa[2][0] + cAa[3][0])) + cAa[4][0];    \
        float yA = fast_tanh(sA + xvA);                                                \
        float yB = 0.f;                                                                \
        if (hasB) {                                                                    \
            float sB = ((cBb[0][0] + cBb[1][0]) + (cBb[2][0] + cBb[3][0])) + cBb[4][0];\
            yB = fast_tanh(sB + xvB);                                                  \
        }                                                                              \
        if (writer) {                                                                  \
            _Float16 hA = (_Float16)yA, hB = (_Float16)yB;                             \
            hlds[1 - (R_)][cA] = hA;                                                   \
            if (hasB) hlds[1 - (R_)][cB] = hB;                                         \
            hseq[(size_t)(t_) * HP + cA] = hA;                                         \
            if (hasB) hseq[(size_t)(t_) * HP + cB] = hB;                               \
        }                                                                              \
    } while (0)

// barrier with LDS drain; "memory" clobber orders memory ops but leaves ALU free to
// schedule into the barrier shadow (vmcnt never drained: x prefetch stays in flight)
#define BAR() asm volatile("s_waitcnt lgkmcnt(0)\n\ts_barrier" ::: "memory")

#pragma unroll 1
    for (int c = 0; c < NCHUNK; ++c) {
        if (!ROLE0 && c > 0) {
            int tgt = (c + 2) < NCHUNK ? (c + 2) : NCHUNK;
            wait_flag(&g_flag1, tgt);
        }
#pragma unroll 1
        for (int tt = 0; tt < CHUNK; tt += DIST) {
            const int tb = c * CHUNK + tt;
            STEP(tb + 0, 0, 0); BAR();
            STEP(tb + 1, 1, 1); BAR();
            STEP(tb + 2, 0, 2); BAR();
            STEP(tb + 3, 1, 3); BAR();
        }
        if (ROLE0) publish_flag(&g_flag0, c + 1);
    }
#undef STEP
#undef BAR
}

// ---------------- proj role: x1[t] = W_ih1 h0[t] + (b_ih1+b_hh1), chunked ----------------
__device__ __forceinline__ void proj_role(const float* __restrict__ Wih,
                                          const float* __restrict__ b1,
                                          const float* __restrict__ b2)
{
    const int tid  = threadIdx.x;
    const int lane = tid & 63;
    const int wave = tid >> 6;       // 0..11
    const int col  = lane & 15;      // timestep-within-16-group (B col / D col)
    const int g    = lane >> 4;      // k-subgroup / D row-group

    const int tA = wave, tB = wave + NWAVE;
    const bool hasB = (wave < 7);

    f16x8 wA[KC], wB[KC];
#pragma unroll
    for (int kc = 0; kc < KC; kc++) {
        wA[kc] = loadw_frag(Wih, tA, col, g, kc);
        if (hasB) wB[kc] = loadw_frag(Wih, tB, col, g, kc);
        else {
            f16x8 z;
#pragma unroll
            for (int j = 0; j < 8; j++) z[j] = (_Float16)0.f;
            wB[kc] = z;
        }
    }
    // bias vectors for this lane's 4 output rows per tile (zero for j>=HID)
    f32x4 bA, bB;
#pragma unroll
    for (int e = 0; e < 4; e++) {
        int jA = tA * 16 + g * 4 + e, jB = tB * 16 + g * 4 + e;
        bA[e] = (jA < HID) ? b1[jA] + b2[jA] : 0.f;
        bB[e] = (hasB && jB < HID) ? b1[jB] + b2[jB] : 0.f;
    }

    const f32x4 zero4 = {0.f, 0.f, 0.f, 0.f};

#pragma unroll 1
    for (int c = 0; c < NCHUNK; ++c) {
        wait_flag(&g_flag0, c + 1);
        const int tbase = c * CHUNK;
#pragma unroll
        for (int tg = 0; tg < 4; ++tg) {
            const int t = tbase + tg * 16 + col;
            f16x8 bf[KC];
#pragma unroll
            for (int kc = 0; kc < KC; ++kc)
                bf[kc] = *(const f16x8*)&g_h0h[(size_t)t * HP + kc * 32 + g * 8];
            f32x4 aA = zero4, aB = zero4;
#pragma unroll
            for (int kc = 0; kc < KC; ++kc) {
                aA = MF(wA[kc], bf[kc], aA);
                if (hasB) aB = MF(wB[kc], bf[kc], aB);
            }
            // D: col=lane&15 -> t, row=g*4+e -> j within tile; f32x4 store per tile
            *(f32x4*)&g_x1[(size_t)t * HP + tA * 16 + g * 4] = aA + bA;
            if (hasB)
            *(f32x4*)&g_x1[(size_t)t * HP + tB * 16 + g * 4] = aB + bB;
        }
        publish_flag(&g_flag1, c + 1);
    }
}

// ---------------- fused pipeline: block0=scan0, block1=proj1, block2=scan1 ----------------
__global__ __launch_bounds__(64 * NWAVE, 3) void k_pipeline(const float* __restrict__ W_hh0,
                                                            const float* __restrict__ W_ih1,
                                                            const float* __restrict__ b_ih1,
                                                            const float* __restrict__ b_hh1,
                                                            const float* __restrict__ W_hh1)
{
    __shared__ __align__(16) _Float16 hlds[2][HK];
    if (blockIdx.x == 0)
        scan_role<1>(hlds, W_hh0, g_x, g_h0h);
    else if (blockIdx.x == 1)
        proj_role(W_ih1, b_ih1, b_hh1);
    else
        scan_role<0>(hlds, W_hh1, g_x1, g_h1h);
}

extern "C" void kernel_launch(void* const* d_in, const int* in_sizes, int n_in,
                              void* d_out, int out_size, void* d_ws, size_t ws_size,
                              hipStream_t stream)
{
    (void)in_sizes; (void)n_in; (void)d_ws; (void)ws_size; (void)out_size;
    const float* input = (const float*)d_in[0];
    const float* W_ih0 = (const float*)d_in[1];
    const float* W_hh0 = (const float*)d_in[2];
    const float* b_ih0 = (const float*)d_in[3];
    const float* b_hh0 = (const float*)d_in[4];
    const float* W_ih1 = (const float*)d_in[5];
    const float* W_hh1 = (const float*)d_in[6];
    const float* b_ih1 = (const float*)d_in[7];
    const float* b_hh1 = (const float*)d_in[8];
    const float* W_lin = (const float*)d_in[9];
    const float* b_lin = (const float*)d_in[10];
    float* out = (float*)d_out;

    k_reset<<<dim3(1), dim3(1), 0, stream>>>();
    k_transpose<<<dim3((IN_D * HP + 255) / 256), dim3(256), 0, stream>>>(W_ih0, HID, IN_D, HP, 0);
    k_transpose<<<dim3((HID * OUTP + 255) / 256), dim3(256), 0, stream>>>(W_lin, OUT_D, HID, OUTP, 2);

    // x0 = input @ W_ih0^T + (b_ih0 + b_hh0)
    k_gemm_in<<<dim3(T_LEN / 32), dim3(320), 0, stream>>>(input, b_ih0, b_hh0);

    // fused scan0 | proj1 | scan1 pipeline (3 co-resident workgroups)
    k_pipeline<<<dim3(3), dim3(64 * NWAVE), 0, stream>>>(W_hh0, W_ih1, b_ih1, b_hh1, W_hh1);

    // head
    k_gemm_out<<<dim3(T_LEN / 64), dim3(128), 0, stream>>>(b_lin, out);
}

// Round 11
// 31855.688 us; speedup vs baseline: 3.9793x; 3.9793x over previous
//
#include <hip/hip_runtime.h>
#include <cstddef>

#define T_LEN 32768
#define HID   300
#define HP    304   // padded row width for x/h buffers
#define HK    320   // padded K for MFMA (10 chunks of 32)
#define KC    10
#define IN_D  500
#define OUT_D 100
#define OUTP  104
#define DIST  2     // x prefetch distance (steps) = slot count
#define CHUNK 64
#define NCHUNK (T_LEN / CHUNK)
#define NWAVE 8     // 512 threads, 2 waves/SIMD (256-reg budget)

typedef _Float16 f16x8 __attribute__((ext_vector_type(8)));
typedef float    f32x4 __attribute__((ext_vector_type(4)));

// Static device scratch
__device__ __align__(16) float    g_x  [(size_t)(T_LEN + 8) * HP];    // x0
__device__ __align__(16) float    g_x1 [(size_t)(T_LEN + 8) * HP];    // x1
__device__ __align__(16) _Float16 g_h0h[(size_t)T_LEN * HP + 64];     // h0, f16
__device__ __align__(16) _Float16 g_h1h[(size_t)T_LEN * HP + 64];     // h1, f16
__device__ __align__(16) float    g_wt0[IN_D * HP];
__device__ __align__(16) float    g_wtl[HID * OUTP];
__device__ int g_flag0;   // chunks of h0 published by scan0
__device__ int g_flag1;   // chunks of x1 published by proj1

// ---------------- reset flags (graph replays!) ----------------
__global__ void k_reset() { g_flag0 = 0; g_flag1 = 0; }

// ---------------- transpose + pad: dst[k][j] = (j<J) ? src[j][k] : 0 ----------------
__global__ void k_transpose(const float* __restrict__ src, int J, int K, int JP, int dst_sel)
{
    float* dst = (dst_sel == 0) ? g_wt0 : g_wtl;
    int idx = blockIdx.x * 256 + threadIdx.x;
    if (idx >= K * JP) return;
    int k = idx / JP, j = idx - k * JP;
    dst[idx] = (j < J) ? src[j * K + k] : 0.f;
}

// ---------------- x0 = input @ W_ih0^T + (b_ih0+b_hh0), 32 rows per block ----------------
__global__ __launch_bounds__(320) void k_gemm_in(const float* __restrict__ inp,
                                                 const float* __restrict__ b1,
                                                 const float* __restrict__ b2)
{
    __shared__ float lds[32 * IN_D];
    const int tid = threadIdx.x;
    const int t0  = blockIdx.x * 32;
    {
        const f32x4* src4 = (const f32x4*)(inp + (size_t)t0 * IN_D);
        f32x4* lds4 = (f32x4*)lds;
        const int n4 = (32 * IN_D) >> 2;
        for (int i = tid; i < n4; i += 320) lds4[i] = src4[i];
    }
    __syncthreads();
    const int j = tid;
    if (j >= HP) return;
    float acc[32];
#pragma unroll
    for (int i = 0; i < 32; i++) acc[i] = 0.f;
#pragma unroll 4
    for (int k = 0; k < IN_D; k++) {
        float w = g_wt0[k * HP + j];
#pragma unroll
        for (int i = 0; i < 32; i++) acc[i] += w * lds[i * IN_D + k];  // uniform addr -> broadcast
    }
    const float bias = (j < HID) ? (b1[j] + b2[j]) : 0.f;
#pragma unroll 4
    for (int i = 0; i < 32; i++) g_x[(size_t)(t0 + i) * HP + j] = acc[i] + bias;
}

// ---------------- out = h1(f16) @ WTl + b_lin, 64 rows per block ----------------
__global__ __launch_bounds__(128) void k_gemm_out(const float* __restrict__ blin,
                                                  float* __restrict__ out)
{
    __shared__ float lds[64 * HP];
    const int tid = threadIdx.x;
    const int t0  = blockIdx.x * 64;
    {
        const f16x8* src8 = (const f16x8*)(g_h1h + (size_t)t0 * HP);
        const int n8 = (64 * HP) / 8;
        for (int i = tid; i < n8; i += 128) {
            f16x8 v = src8[i];
            float* d = &lds[i * 8];
#pragma unroll
            for (int e = 0; e < 8; e++) d[e] = (float)v[e];
        }
    }
    __syncthreads();
    const int j = tid;
    if (j >= OUTP) return;
    float acc[64];
#pragma unroll
    for (int i = 0; i < 64; i++) acc[i] = 0.f;
#pragma unroll 2
    for (int k = 0; k < HID; k++) {
        float w = g_wtl[k * OUTP + j];
#pragma unroll
        for (int i = 0; i < 64; i++) acc[i] += w * lds[i * HP + k];
    }
    if (j < OUT_D) {
        float b = blin[j];
        for (int i = 0; i < 64; i++) out[(size_t)(t0 + i) * OUT_D + j] = acc[i] + b;
    }
}

// ---------------- helpers ----------------
__device__ __forceinline__ float fast_tanh(float v)
{
    float e = __expf(2.f * v);
    return 1.f - 2.f * __builtin_amdgcn_rcpf(e + 1.f);
}

// W row-tile fragment as f16: lane holds row = tile*16+col, k = kc*32+g*8+j; OOB zeroed.
// Same register contents serve as A-frag (row=l&15) or B-frag (col=l&15).
__device__ __forceinline__ f16x8 loadw_frag(const float* __restrict__ W,
                                            int tile, int col, int g, int kc)
{
    const int row = tile * 16 + col;
    const int kb  = kc * 32 + g * 8;
    f16x8 f;
#pragma unroll
    for (int j = 0; j < 8; j++) {
        const int k = kb + j;
        float wv = (row < HID && k < HID) ? W[row * HID + k] : 0.f;
        f[j] = (_Float16)wv;
    }
    return f;
}

// consumer: tid0 spins with agent-scope acquire (buffer_inv), then block-wide barrier
__device__ __forceinline__ void wait_flag(int* f, int target)
{
    if (threadIdx.x == 0) {
        while (__hip_atomic_load(f, __ATOMIC_ACQUIRE, __HIP_MEMORY_SCOPE_AGENT) < target)
            __builtin_amdgcn_s_sleep(8);
    }
    __syncthreads();
}

// producer: __syncthreads drains each wave's vmcnt; release store (wbl2) publishes
__device__ __forceinline__ void publish_flag(int* f, int v)
{
    __syncthreads();
    if (threadIdx.x == 0)
        __hip_atomic_store(f, v, __ATOMIC_RELEASE, __HIP_MEMORY_SCOPE_AGENT);
}

#define MF(a_, b_, c_) __builtin_amdgcn_mfma_f32_16x16x32_f16((a_), (b_), (c_), 0, 0, 0)

// ---------------- scan role: h_t = tanh(x_t + Whh h_{t-1}) ----------------
// 8 waves (2/SIMD), 2-way K-SPLIT: group = wave>>2 (0: kc 0-4 + finalize; 1: kc 5-9,
// writes partials). Pair p = wave&3 covers tiles {p, p+4, p+8, p+12, p+16} (p=3: 4
// tiles, tile 19 is pure pad). Per wave per step: only 5 ds_read_b128 (total 40/step,
// 1/3 of R8's 120 -> LDS queue floor ~480 cy). OPERAND-SWAPPED MFMA (D replicated
// across rows -> scalar extraction acc[0]); 2 chains/tile depth {3,2}. Group 1 writes
// f32 partials to psc (b32, conflict-free); BAR; group 0 reads partial, adds own,
// tanh, publishes f16 h to hlds[1-R] + global; BAR.
template<int ROLE0>
__device__ __forceinline__ void scan_role(_Float16 (*hlds)[HK],
                                          float* psc,
                                          const float* __restrict__ Whh,
                                          const float* __restrict__ xin,
                                          _Float16* __restrict__ hseq)
{
    const int tid  = threadIdx.x;
    const int lane = tid & 63;
    const int wave = tid >> 6;       // 0..7
    const int col  = lane & 15;
    const int g    = lane >> 4;      // 0..3
    const bool writer = (lane < 16);

    const int grp = wave >> 2;       // 0 or 1 (K half)
    const int p   = wave & 3;        // pair index
    const int kb0 = grp * 5;         // kc base: 0 or 5
    const bool hasT4 = (p < 3);      // 5th tile exists (tile 19 = pad, dropped)

    int trow[5];
#pragma unroll
    for (int i = 0; i < 5; i++) trow[i] = (p + 4 * i) * 16 + col;   // <= 303 < HP

    // zero both h LDS buffers (incl. pads)
    for (int i = tid; i < 2 * HK; i += 64 * NWAVE) ((_Float16*)hlds)[i] = (_Float16)0.f;

    // W fragments for this wave's K-half: w[tile][kc_local]
    f16x8 w[5][5];
#pragma unroll
    for (int i = 0; i < 5; i++) {
#pragma unroll
        for (int kc = 0; kc < 5; kc++) {
            if (i == 4 && !hasT4) {
                f16x8 z;
#pragma unroll
                for (int j = 0; j < 8; j++) z[j] = (_Float16)0.f;
                w[i][kc] = z;
            } else {
                w[i][kc] = loadw_frag(Whh, p + 4 * i, col, g, kb0 + kc);
            }
        }
    }

    __syncthreads();

    if (!ROLE0) wait_flag(&g_flag1, NCHUNK < 2 ? NCHUNK : 2);  // chunks 0,1 of x1 ready

    // x prefetch slots (group 0 only; slot s = t & 1)
    float xs[5][DIST];
#pragma unroll
    for (int i = 0; i < 5; i++)
#pragma unroll
        for (int s = 0; s < DIST; s++) xs[i][s] = 0.f;
    if (grp == 0) {
#pragma unroll
        for (int s = 0; s < DIST; s++)
#pragma unroll
            for (int i = 0; i < 5; i++)
                if (i < 4 || hasT4) xs[i][s] = xin[(size_t)s * HP + trow[i]];
    }

    const f32x4 Z = {0.f, 0.f, 0.f, 0.f};

// barrier with LDS drain; "memory" clobber orders memory ops but leaves ALU free
// (vmcnt never drained: x prefetch / h global stores stay in flight)
#define BAR() asm volatile("s_waitcnt lgkmcnt(0)\n\ts_barrier" ::: "memory")

// One timestep, two phases. Phase 1: 5 bf reads, partial MFMAs (2 chains depth 3+2,
// swapped operands), group1 writers publish f32 partials. BAR. Phase 2: group0
// writers read partner partial, add, tanh, publish f16 h to hlds[1-R] + global. BAR.
#define STEP(t_, R_, s_) do {                                                          \
        f16x8 bf[5];                                                                   \
        _Pragma("unroll")                                                              \
        for (int kc = 0; kc < 5; kc++)                                                 \
            bf[kc] = *(const f16x8*)&hlds[R_][(kb0 + kc) * 32 + g * 8];                \
        float xv[5];                                                                   \
        if (grp == 0) {                                                                \
            _Pragma("unroll")                                                          \
            for (int i = 0; i < 5; i++) {                                              \
                xv[i] = xs[i][s_];                                                     \
                if (i < 4 || hasT4)                                                    \
                    xs[i][s_] = xin[(size_t)((t_) + DIST) * HP + trow[i]];             \
            }                                                                          \
        }                                                                              \
        float part[5];                                                                 \
        _Pragma("unroll")                                                              \
        for (int i = 0; i < 5; i++) {                                                  \
            f32x4 a0 = MF(bf[0], w[i][0], Z);                                          \
            f32x4 a1 = MF(bf[3], w[i][3], Z);                                          \
            a0 = MF(bf[1], w[i][1], a0);                                               \
            a1 = MF(bf[4], w[i][4], a1);                                               \
            a0 = MF(bf[2], w[i][2], a0);                                               \
            part[i] = a0[0] + a1[0];                                                   \
        }                                                                              \
        if (grp == 1 && writer) {                                                      \
            _Pragma("unroll")                                                          \
            for (int i = 0; i < 5; i++)                                                \
                if (i < 4 || hasT4) psc[trow[i]] = part[i];                            \
        }                                                                              \
        BAR();                                                                         \
        if (grp == 0 && writer) {                                                      \
            _Pragma("unroll")                                                          \
            for (int i = 0; i < 5; i++) {                                              \
                if (i < 4 || hasT4) {                                                  \
                    float pr = psc[trow[i]];                                           \
                    float y  = fast_tanh(part[i] + pr + xv[i]);                        \
                    _Float16 hy = (_Float16)y;                                         \
                    hlds[1 - (R_)][trow[i]] = hy;                                      \
                    hseq[(size_t)(t_) * HP + trow[i]] = hy;                            \
                }                                                                      \
            }                                                                          \
        }                                                                              \
        BAR();                                                                         \
    } while (0)

#pragma unroll 1
    for (int c = 0; c < NCHUNK; ++c) {
        if (!ROLE0 && c > 0) {
            int tgt = (c + 2) < NCHUNK ? (c + 2) : NCHUNK;
            wait_flag(&g_flag1, tgt);
        }
#pragma unroll 1
        for (int tt = 0; tt < CHUNK; tt += 2) {
            const int tb = c * CHUNK + tt;
            STEP(tb + 0, 0, 0);
            STEP(tb + 1, 1, 1);
        }
        if (ROLE0) publish_flag(&g_flag0, c + 1);
    }
#undef STEP
#undef BAR
}

// ---------------- proj role: x1[t] = W_ih1 h0[t] + (b_ih1+b_hh1), chunked ----------------
// 8 waves: tiles {w, w+8, (w<3): w+16}.
__device__ __forceinline__ void proj_role(const float* __restrict__ Wih,
                                          const float* __restrict__ b1,
                                          const float* __restrict__ b2)
{
    const int tid  = threadIdx.x;
    const int lane = tid & 63;
    const int wave = tid >> 6;       // 0..7
    const int col  = lane & 15;      // timestep-within-16-group (B col / D col)
    const int g    = lane >> 4;      // k-subgroup / D row-group

    const int tA = wave, tB = wave + 8, tC = wave + 16;
    const bool hasC = (wave < 3);

    f16x8 wA[KC], wB[KC], wC[KC];
#pragma unroll
    for (int kc = 0; kc < KC; kc++) {
        wA[kc] = loadw_frag(Wih, tA, col, g, kc);
        wB[kc] = loadw_frag(Wih, tB, col, g, kc);
        if (hasC) wC[kc] = loadw_frag(Wih, tC, col, g, kc);
        else {
            f16x8 z;
#pragma unroll
            for (int j = 0; j < 8; j++) z[j] = (_Float16)0.f;
            wC[kc] = z;
        }
    }
    // bias vectors for this lane's 4 output rows per tile (zero for j>=HID)
    f32x4 bA, bB, bC;
#pragma unroll
    for (int e = 0; e < 4; e++) {
        int jA = tA * 16 + g * 4 + e, jB = tB * 16 + g * 4 + e, jC = tC * 16 + g * 4 + e;
        bA[e] = (jA < HID) ? b1[jA] + b2[jA] : 0.f;
        bB[e] = (jB < HID) ? b1[jB] + b2[jB] : 0.f;
        bC[e] = (hasC && jC < HID) ? b1[jC] + b2[jC] : 0.f;
    }

    const f32x4 zero4 = {0.f, 0.f, 0.f, 0.f};

#pragma unroll 1
    for (int c = 0; c < NCHUNK; ++c) {
        wait_flag(&g_flag0, c + 1);
        const int tbase = c * CHUNK;
#pragma unroll
        for (int tg = 0; tg < 4; ++tg) {
            const int t = tbase + tg * 16 + col;
            f16x8 bf[KC];
#pragma unroll
            for (int kc = 0; kc < KC; ++kc)
                bf[kc] = *(const f16x8*)&g_h0h[(size_t)t * HP + kc * 32 + g * 8];
            f32x4 aA = zero4, aB = zero4, aC = zero4;
#pragma unroll
            for (int kc = 0; kc < KC; ++kc) {
                aA = MF(wA[kc], bf[kc], aA);
                aB = MF(wB[kc], bf[kc], aB);
                if (hasC) aC = MF(wC[kc], bf[kc], aC);
            }
            // D: col=lane&15 -> t, row=g*4+e -> j within tile; f32x4 store per tile
            *(f32x4*)&g_x1[(size_t)t * HP + tA * 16 + g * 4] = aA + bA;
            *(f32x4*)&g_x1[(size_t)t * HP + tB * 16 + g * 4] = aB + bB;
            if (hasC)
            *(f32x4*)&g_x1[(size_t)t * HP + tC * 16 + g * 4] = aC + bC;
        }
        publish_flag(&g_flag1, c + 1);
    }
}

// ---------------- fused pipeline: block0=scan0, block1=proj1, block2=scan1 ----------------
__global__ __launch_bounds__(64 * NWAVE, 2) void k_pipeline(const float* __restrict__ W_hh0,
                                                            const float* __restrict__ W_ih1,
                                                            const float* __restrict__ b_ih1,
                                                            const float* __restrict__ b_hh1,
                                                            const float* __restrict__ W_hh1)
{
    __shared__ __align__(16) _Float16 hlds[2][HK];
    __shared__ __align__(16) float    psc[19 * 16];
    if (blockIdx.x == 0)
        scan_role<1>(hlds, psc, W_hh0, g_x, g_h0h);
    else if (blockIdx.x == 1)
        proj_role(W_ih1, b_ih1, b_hh1);
    else
        scan_role<0>(hlds, psc, W_hh1, g_x1, g_h1h);
}

extern "C" void kernel_launch(void* const* d_in, const int* in_sizes, int n_in,
                              void* d_out, int out_size, void* d_ws, size_t ws_size,
                              hipStream_t stream)
{
    (void)in_sizes; (void)n_in; (void)d_ws; (void)ws_size; (void)out_size;
    const float* input = (const float*)d_in[0];
    const float* W_ih0 = (const float*)d_in[1];
    const float* W_hh0 = (const float*)d_in[2];
    const float* b_ih0 = (const float*)d_in[3];
    const float* b_hh0 = (const float*)d_in[4];
    const float* W_ih1 = (const float*)d_in[5];
    const float* W_hh1 = (const float*)d_in[6];
    const float* b_ih1 = (const float*)d_in[7];
    const float* b_hh1 = (const float*)d_in[8];
    const float* W_lin = (const float*)d_in[9];
    const float* b_lin = (const float*)d_in[10];
    float* out = (float*)d_out;

    k_reset<<<dim3(1), dim3(1), 0, stream>>>();
    k_transpose<<<dim3((IN_D * HP + 255) / 256), dim3(256), 0, stream>>>(W_ih0, HID, IN_D, HP, 0);
    k_transpose<<<dim3((HID * OUTP + 255) / 256), dim3(256), 0, stream>>>(W_lin, OUT_D, HID, OUTP, 2);

    // x0 = input @ W_ih0^T + (b_ih0 + b_hh0)
    k_gemm_in<<<dim3(T_LEN / 32), dim3(320), 0, stream>>>(input, b_ih0, b_hh0);

    // fused scan0 | proj1 | scan1 pipeline (3 co-resident workgroups)
    k_pipeline<<<dim3(3), dim3(64 * NWAVE), 0, stream>>>(W_hh0, W_ih1, b_ih1, b_hh1, W_hh1);

    // head
    k_gemm_out<<<dim3(T_LEN / 64), dim3(128), 0, stream>>>(b_lin, out);
}